// Round 1
// baseline (26682.684 us; speedup 1.0000x reference)
//
#include <hip/hip_runtime.h>
#include <hip/hip_bf16.h>

// CLIP ViT-B/16 visual forward. Round 0: correct f32 baseline.
// L=12, D=768, H=12, DH=64, FF=3072, PATCH=16, IMG=224, B=32, S=197, OUT=512.

#define LAYERS 12
#define DMODEL 768
#define NHEADS 12
#define DHEAD  64
#define FFDIM  3072
#define BATCH  32
#define SEQ    197
#define NPATCH 196
#define OUTD   512
#define MROWS  (BATCH * SEQ)   // 6304

// ---------------------------------------------------------------- patch embed
__global__ __launch_bounds__(256) void patch_embed_kernel(
    const float* __restrict__ x_inp,   // [32,3,224,224]
    const float* __restrict__ conv_w,  // [768, 768] (O, I*16*16)
    const float* __restrict__ pos_emb, // [197,768]
    float* __restrict__ x)             // [32,197,768]
{
    int p = blockIdx.x;   // 0..195
    int b = blockIdx.y;   // 0..31
    int py = p / 14, px = p % 14;
    __shared__ float patch[768];
    int t = threadIdx.x;
    const float* xb = x_inp + (long)b * 3 * 224 * 224;
    for (int e = t; e < 768; e += 256) {
        int c = e >> 8, i = (e >> 4) & 15, j = e & 15;
        patch[e] = xb[((long)c * 224 + py * 16 + i) * 224 + px * 16 + j];
    }
    __syncthreads();
    for (int d = t; d < 768; d += 256) {
        const float* wrow = conv_w + (long)d * 768;
        float s = 0.f;
        #pragma unroll 8
        for (int k = 0; k < 768; k += 4) {
            float4 wv = *reinterpret_cast<const float4*>(&wrow[k]);
            s += patch[k] * wv.x + patch[k+1] * wv.y + patch[k+2] * wv.z + patch[k+3] * wv.w;
        }
        x[((long)(b * SEQ + 1 + p)) * DMODEL + d] = s + pos_emb[(long)(1 + p) * DMODEL + d];
    }
}

__global__ __launch_bounds__(256) void cls_token_kernel(
    const float* __restrict__ cls_emb, const float* __restrict__ pos_emb,
    float* __restrict__ x)
{
    int b = blockIdx.x;
    for (int d = threadIdx.x; d < DMODEL; d += 256)
        x[(long)b * SEQ * DMODEL + d] = cls_emb[d] + pos_emb[d];
}

// ---------------------------------------------------------------- layernorm
// one block (256 threads) per row of 768
__global__ __launch_bounds__(256) void ln_kernel(
    const float* __restrict__ in, float* __restrict__ out,
    const float* __restrict__ w, const float* __restrict__ bb,
    long in_stride, long out_stride)
{
    int row = blockIdx.x;
    const float* xr = in + (long)row * in_stride;
    float* orow = out + (long)row * out_stride;
    int t = threadIdx.x;
    int lane = t & 63, wid = t >> 6;
    __shared__ float red[8];

    float v[3];
    float s = 0.f;
    #pragma unroll
    for (int i = 0; i < 3; ++i) { v[i] = xr[t + i * 256]; s += v[i]; }
    #pragma unroll
    for (int off = 32; off; off >>= 1) s += __shfl_xor(s, off);
    if (lane == 0) red[wid] = s;
    __syncthreads();
    float mean = (red[0] + red[1] + red[2] + red[3]) * (1.0f / DMODEL);
    float sq = 0.f;
    #pragma unroll
    for (int i = 0; i < 3; ++i) { float d = v[i] - mean; sq += d * d; }
    #pragma unroll
    for (int off = 32; off; off >>= 1) sq += __shfl_xor(sq, off);
    if (lane == 0) red[4 + wid] = sq;
    __syncthreads();
    float rstd = rsqrtf((red[4] + red[5] + red[6] + red[7]) * (1.0f / DMODEL) + 1e-5f);
    #pragma unroll
    for (int i = 0; i < 3; ++i) {
        int d = t + i * 256;
        orow[d] = (v[i] - mean) * rstd * w[d] + bb[d];
    }
}

// ---------------------------------------------------------------- GEMM (f32)
// C[M,N] = A[M,K] @ W[N,K]^T + bias  (ACCUM: C += ..., GELU: quickgelu)
// 64x64 tile, 256 threads, 4x4 per thread.
template<int ACCUM, int GELU>
__global__ __launch_bounds__(256) void gemm_nt(
    const float* __restrict__ A, const float* __restrict__ W,
    const float* __restrict__ bias, float* __restrict__ C,
    int M, int N, int K)
{
    __shared__ float As[16][64];
    __shared__ float Bs[16][64];
    int bm = blockIdx.x * 64;
    int bn = blockIdx.y * 64;
    int tid = threadIdx.x;
    int tx = tid & 15, ty = tid >> 4;
    float acc[4][4] = {};

    int e = tid * 4;
    int lr = e >> 4;          // row within tile 0..63
    int lc = e & 15;          // col (k) within tile, multiple of 4
    for (int kt = 0; kt < K; kt += 16) {
        float4 av = make_float4(0.f, 0.f, 0.f, 0.f);
        int arow = bm + lr;
        if (arow < M) av = *reinterpret_cast<const float4*>(&A[(long)arow * K + kt + lc]);
        As[lc + 0][lr] = av.x; As[lc + 1][lr] = av.y;
        As[lc + 2][lr] = av.z; As[lc + 3][lr] = av.w;
        float4 wv = *reinterpret_cast<const float4*>(&W[(long)(bn + lr) * K + kt + lc]);
        Bs[lc + 0][lr] = wv.x; Bs[lc + 1][lr] = wv.y;
        Bs[lc + 2][lr] = wv.z; Bs[lc + 3][lr] = wv.w;
        __syncthreads();
        #pragma unroll
        for (int kk = 0; kk < 16; ++kk) {
            float4 a4 = *reinterpret_cast<const float4*>(&As[kk][ty * 4]);
            float4 b4 = *reinterpret_cast<const float4*>(&Bs[kk][tx * 4]);
            float a[4] = {a4.x, a4.y, a4.z, a4.w};
            float bvv[4] = {b4.x, b4.y, b4.z, b4.w};
            #pragma unroll
            for (int i = 0; i < 4; ++i)
                #pragma unroll
                for (int j = 0; j < 4; ++j)
                    acc[i][j] += a[i] * bvv[j];
        }
        __syncthreads();
    }
    #pragma unroll
    for (int i = 0; i < 4; ++i) {
        int row = bm + ty * 4 + i;
        if (row >= M) break;
        #pragma unroll
        for (int j = 0; j < 4; ++j) {
            int col = bn + tx * 4 + j;
            float v = acc[i][j] + bias[col];
            if (GELU) v = v / (1.0f + __expf(-1.702f * v));
            long idx = (long)row * N + col;
            if (ACCUM) C[idx] += v; else C[idx] = v;
        }
    }
}

// ---------------------------------------------------------------- attention
// one wave per (b, h, q-row)
__global__ __launch_bounds__(64) void attn_kernel(
    const float* __restrict__ qkv,  // [B*S, 2304]
    float* __restrict__ o)          // [B*S, 768]
{
    int q = blockIdx.x;       // 0..196
    int bh = blockIdx.y;      // 0..383
    int b = bh / NHEADS, h = bh % NHEADS;
    int t = threadIdx.x;
    __shared__ float qs[64];
    __shared__ float sc[SEQ];
    const float scale = 0.125f;   // 64^-0.5

    const float* qrow = qkv + ((long)(b * SEQ + q)) * 2304 + h * 64;
    qs[t] = qrow[t] * scale;
    __syncthreads();

    const float* kbase = qkv + (long)b * SEQ * 2304 + 768 + h * 64;
    for (int k0 = t; k0 < SEQ; k0 += 64) {
        const float* krow = kbase + (long)k0 * 2304;
        float s = 0.f;
        #pragma unroll
        for (int d = 0; d < 64; d += 4) {
            float4 kv = *reinterpret_cast<const float4*>(&krow[d]);
            s += qs[d] * kv.x + qs[d+1] * kv.y + qs[d+2] * kv.z + qs[d+3] * kv.w;
        }
        sc[k0] = s;
    }
    __syncthreads();

    float m = -1e30f;
    for (int k0 = t; k0 < SEQ; k0 += 64) m = fmaxf(m, sc[k0]);
    #pragma unroll
    for (int off = 32; off; off >>= 1) m = fmaxf(m, __shfl_xor(m, off));
    float sum = 0.f;
    for (int k0 = t; k0 < SEQ; k0 += 64) {
        float ev = __expf(sc[k0] - m);
        sc[k0] = ev;
        sum += ev;
    }
    #pragma unroll
    for (int off = 32; off; off >>= 1) sum += __shfl_xor(sum, off);
    float inv = 1.0f / sum;
    __syncthreads();

    const float* vbase = qkv + (long)b * SEQ * 2304 + 1536 + h * 64;
    float accv = 0.f;
    for (int k = 0; k < SEQ; ++k)
        accv += sc[k] * vbase[(long)k * 2304 + t];
    o[((long)(b * SEQ + q)) * DMODEL + h * 64 + t] = accv * inv;
}

// ---------------------------------------------------------------- final proj
__global__ __launch_bounds__(256) void proj_kernel(
    const float* __restrict__ cls_ln,  // [32,768]
    const float* __restrict__ proj,    // [768,512]
    float* __restrict__ out)           // [32,512]
{
    int idx = blockIdx.x * 256 + threadIdx.x;   // 0..16383
    int m = idx >> 9, n = idx & 511;
    float s = 0.f;
    #pragma unroll 8
    for (int k = 0; k < 768; ++k)
        s += cls_ln[m * 768 + k] * proj[k * 512 + n];
    out[idx] = s;
}

// ---------------------------------------------------------------- launcher
extern "C" void kernel_launch(void* const* d_in, const int* in_sizes, int n_in,
                              void* d_out, int out_size, void* d_ws, size_t ws_size,
                              hipStream_t stream) {
    const float* x_inp    = (const float*)d_in[0];
    const float* conv_w   = (const float*)d_in[1];
    const float* cls_emb  = (const float*)d_in[2];
    const float* pos_emb  = (const float*)d_in[3];
    const float* ln_pre_w = (const float*)d_in[4];
    const float* ln_pre_b = (const float*)d_in[5];
    const float* ln1_w    = (const float*)d_in[6];
    const float* ln1_b    = (const float*)d_in[7];
    const float* qkv_w    = (const float*)d_in[8];
    const float* qkv_b    = (const float*)d_in[9];
    const float* out_w    = (const float*)d_in[10];
    const float* out_b    = (const float*)d_in[11];
    const float* ln2_w    = (const float*)d_in[12];
    const float* ln2_b    = (const float*)d_in[13];
    const float* fc1_w    = (const float*)d_in[14];
    const float* fc1_b    = (const float*)d_in[15];
    const float* fc2_w    = (const float*)d_in[16];
    const float* fc2_b    = (const float*)d_in[17];
    const float* ln_post_w= (const float*)d_in[18];
    const float* ln_post_b= (const float*)d_in[19];
    const float* proj     = (const float*)d_in[20];

    float* ws = (float*)d_ws;
    float* x    = ws;                          // MROWS*768
    float* y    = x + (long)MROWS * DMODEL;    // MROWS*768
    float* big  = y + (long)MROWS * DMODEL;    // MROWS*3072 (qkv [MROWS*2304] shares)
    float* clsb = big + (long)MROWS * FFDIM;   // 32*768
    // total ~116.4 MB

    // patch embed + cls + pos, then ln_pre in place
    patch_embed_kernel<<<dim3(NPATCH, BATCH), 256, 0, stream>>>(x_inp, conv_w, pos_emb, x);
    cls_token_kernel<<<BATCH, 256, 0, stream>>>(cls_emb, pos_emb, x);
    ln_kernel<<<MROWS, 256, 0, stream>>>(x, x, ln_pre_w, ln_pre_b, DMODEL, DMODEL);

    const int GM = (MROWS + 63) / 64;   // 99
    for (int l = 0; l < LAYERS; ++l) {
        ln_kernel<<<MROWS, 256, 0, stream>>>(x, y, ln1_w + l * DMODEL, ln1_b + l * DMODEL,
                                             DMODEL, DMODEL);
        gemm_nt<0, 0><<<dim3(GM, 2304 / 64), 256, 0, stream>>>(
            y, qkv_w + (long)l * 2304 * DMODEL, qkv_b + (long)l * 2304, big,
            MROWS, 2304, DMODEL);
        attn_kernel<<<dim3(SEQ, BATCH * NHEADS), 64, 0, stream>>>(big, y);
        gemm_nt<1, 0><<<dim3(GM, DMODEL / 64), 256, 0, stream>>>(
            y, out_w + (long)l * DMODEL * DMODEL, out_b + (long)l * DMODEL, x,
            MROWS, DMODEL, DMODEL);
        ln_kernel<<<MROWS, 256, 0, stream>>>(x, y, ln2_w + l * DMODEL, ln2_b + l * DMODEL,
                                             DMODEL, DMODEL);
        gemm_nt<0, 1><<<dim3(GM, FFDIM / 64), 256, 0, stream>>>(
            y, fc1_w + (long)l * FFDIM * DMODEL, fc1_b + (long)l * FFDIM, big,
            MROWS, FFDIM, DMODEL);
        gemm_nt<1, 0><<<dim3(GM, DMODEL / 64), 256, 0, stream>>>(
            big, fc2_w + (long)l * DMODEL * FFDIM, fc2_b + (long)l * DMODEL, x,
            MROWS, DMODEL, FFDIM);
    }

    // ln_post on cls rows (row b at x + b*SEQ*768), then projection
    ln_kernel<<<BATCH, 256, 0, stream>>>(x, clsb, ln_post_w, ln_post_b,
                                         (long)SEQ * DMODEL, DMODEL);
    proj_kernel<<<(BATCH * OUTD) / 256, 256, 0, stream>>>(clsb, proj, (float*)d_out);
}